// Round 1
// baseline (245.794 us; speedup 1.0000x reference)
//
#include <hip/hip_runtime.h>
#include <hip/hip_bf16.h>

typedef __attribute__((ext_vector_type(8))) short short8;
typedef __attribute__((ext_vector_type(4))) float f32x4;

#define MFMA16(A, B, C) __builtin_amdgcn_mfma_f32_16x16x32_bf16(A, B, C, 0, 0, 0)

#define SEQ 2048
#define DM 512
#define NH 8
#define DK 64
#define NROWS 4096  // B*S

__device__ __forceinline__ short f2bf(float f) {
  union { float f; unsigned u; } x; x.f = f;
  unsigned r = (x.u + 0x7fffu + ((x.u >> 16) & 1u)) >> 16;
  return (short)r;
}

// ---------------------------------------------------------------------------
// Kernel 1: QKV projection. out[n][o] = sum_d X[n][d] * W[o][d] + b[o]
// z=0: Q -> [B,H,S,DK] bf16 ; z=1: K -> [B,H,S,DK] ; z=2: V -> [B,H,DK,S] (T)
// ---------------------------------------------------------------------------
__global__ __launch_bounds__(256) void qkv_proj_kernel(
    const float* __restrict__ qin, const float* __restrict__ kin, const float* __restrict__ vin,
    const float* __restrict__ Wq, const float* __restrict__ Wk, const float* __restrict__ Wv,
    const float* __restrict__ bq, const float* __restrict__ bk, const float* __restrict__ bv,
    short* __restrict__ Qb, short* __restrict__ Kb, short* __restrict__ Vtb)
{
  int z = blockIdx.z;
  const float* X    = (z == 0) ? qin : (z == 1) ? kin : vin;
  const float* W    = (z == 0) ? Wq  : (z == 1) ? Wk  : Wv;
  const float* bias = (z == 0) ? bq  : (z == 1) ? bk  : bv;

  __shared__ short As[64][40];
  __shared__ short Bs[64][40];

  int t = threadIdx.x;
  int lane = t & 63, wave = t >> 6;
  int wr = wave >> 1, wc = wave & 1;
  int fr = lane & 15, fg = lane >> 4;
  int m0 = blockIdx.x * 64, n0 = blockIdx.y * 64;
  int lrow = t >> 2, lcol = (t & 3) * 8;

  f32x4 acc[2][2] = {};

  for (int k0 = 0; k0 < DM; k0 += 32) {
    __syncthreads();
    {
      const float* ap = X + (size_t)(m0 + lrow) * DM + k0 + lcol;
      float4 f0 = *(const float4*)ap;
      float4 f1 = *(const float4*)(ap + 4);
      short8 s;
      s[0] = f2bf(f0.x); s[1] = f2bf(f0.y); s[2] = f2bf(f0.z); s[3] = f2bf(f0.w);
      s[4] = f2bf(f1.x); s[5] = f2bf(f1.y); s[6] = f2bf(f1.z); s[7] = f2bf(f1.w);
      *(short8*)&As[lrow][lcol] = s;
      const float* bp = W + (size_t)(n0 + lrow) * DM + k0 + lcol;
      float4 g0 = *(const float4*)bp;
      float4 g1 = *(const float4*)(bp + 4);
      short8 sb;
      sb[0] = f2bf(g0.x); sb[1] = f2bf(g0.y); sb[2] = f2bf(g0.z); sb[3] = f2bf(g0.w);
      sb[4] = f2bf(g1.x); sb[5] = f2bf(g1.y); sb[6] = f2bf(g1.z); sb[7] = f2bf(g1.w);
      *(short8*)&Bs[lrow][lcol] = sb;
    }
    __syncthreads();
    short8 a0 = *(const short8*)&As[wr * 32 + fr][fg * 8];
    short8 a1 = *(const short8*)&As[wr * 32 + 16 + fr][fg * 8];
    short8 b0 = *(const short8*)&Bs[wc * 32 + fr][fg * 8];
    short8 b1 = *(const short8*)&Bs[wc * 32 + 16 + fr][fg * 8];
    acc[0][0] = MFMA16(a0, b0, acc[0][0]);
    acc[0][1] = MFMA16(a0, b1, acc[0][1]);
    acc[1][0] = MFMA16(a1, b0, acc[1][0]);
    acc[1][1] = MFMA16(a1, b1, acc[1][1]);
  }

#pragma unroll
  for (int mi = 0; mi < 2; mi++)
#pragma unroll
    for (int ni = 0; ni < 2; ni++)
#pragma unroll
      for (int r = 0; r < 4; r++) {
        int row = m0 + wr * 32 + mi * 16 + fg * 4 + r;
        int col = n0 + wc * 32 + ni * 16 + fr;
        float val = acc[mi][ni][r] + bias[col];
        int bb = row >> 11, s = row & 2047, h = col >> 6, dk = col & 63;
        short o = f2bf(val);
        if (z == 0)      Qb[((size_t)(bb * NH + h) * SEQ + s) * DK + dk] = o;
        else if (z == 1) Kb[((size_t)(bb * NH + h) * SEQ + s) * DK + dk] = o;
        else             Vtb[((size_t)(bb * NH + h) * DK + dk) * SEQ + s] = o;
      }
}

// ---------------------------------------------------------------------------
// Kernel 2: attention. Per (b,h) and 16-q-row wave: two-pass online softmax.
// Writes attn (f32, [B,H,S,S]) and ctx (bf16, [B,S,DM], pre-Wo).
// ---------------------------------------------------------------------------
__global__ __launch_bounds__(256) void attn_kernel(
    const short* __restrict__ Q, const short* __restrict__ K, const short* __restrict__ Vt,
    float* __restrict__ attn, short* __restrict__ ctx)
{
  int t = threadIdx.x, lane = t & 63, wave = t >> 6;
  int fr = lane & 15, fg = lane >> 4;
  int bh = blockIdx.y;
  const short* Qh = Q + (size_t)bh * SEQ * DK;
  const short* Kh = K + (size_t)bh * SEQ * DK;
  const short* Vh = Vt + (size_t)bh * DK * SEQ;
  int q0 = blockIdx.x * 64 + wave * 16;

  short8 qa0 = *(const short8*)(Qh + (q0 + fr) * DK + fg * 8);
  short8 qa1 = *(const short8*)(Qh + (q0 + fr) * DK + 32 + fg * 8);

  float m[4], sden[4];
#pragma unroll
  for (int r = 0; r < 4; r++) { m[r] = -1e30f; sden[r] = 0.f; }

  // Pass A: row max + denominator (online)
  for (int kb = 0; kb < SEQ; kb += 32) {
    f32x4 sc[2];
#pragma unroll
    for (int ct = 0; ct < 2; ct++) {
      const short* kp = Kh + (kb + ct * 16 + fr) * DK;
      short8 k0v = *(const short8*)(kp + fg * 8);
      short8 k1v = *(const short8*)(kp + 32 + fg * 8);
      f32x4 zz = {0.f, 0.f, 0.f, 0.f};
      zz = MFMA16(qa0, k0v, zz);
      zz = MFMA16(qa1, k1v, zz);
      sc[ct] = zz * 0.125f;
    }
#pragma unroll
    for (int r = 0; r < 4; r++) {
      float bmax = fmaxf(sc[0][r], sc[1][r]);
      bmax = fmaxf(bmax, __shfl_xor(bmax, 1));
      bmax = fmaxf(bmax, __shfl_xor(bmax, 2));
      bmax = fmaxf(bmax, __shfl_xor(bmax, 4));
      bmax = fmaxf(bmax, __shfl_xor(bmax, 8));
      float mn = fmaxf(m[r], bmax);
      float e = __expf(sc[0][r] - mn) + __expf(sc[1][r] - mn);
      e += __shfl_xor(e, 1);
      e += __shfl_xor(e, 2);
      e += __shfl_xor(e, 4);
      e += __shfl_xor(e, 8);
      sden[r] = sden[r] * __expf(m[r] - mn) + e;
      m[r] = mn;
    }
  }
  float rden[4];
#pragma unroll
  for (int r = 0; r < 4; r++) rden[r] = 1.f / sden[r];

  // Pass B: recompute scores, write attn, PV accumulate
  f32x4 oacc[4] = {};
  __shared__ short P[4][16][40];
  for (int kb = 0; kb < SEQ; kb += 32) {
    f32x4 sc[2];
#pragma unroll
    for (int ct = 0; ct < 2; ct++) {
      const short* kp = Kh + (kb + ct * 16 + fr) * DK;
      short8 k0v = *(const short8*)(kp + fg * 8);
      short8 k1v = *(const short8*)(kp + 32 + fg * 8);
      f32x4 zz = {0.f, 0.f, 0.f, 0.f};
      zz = MFMA16(qa0, k0v, zz);
      zz = MFMA16(qa1, k1v, zz);
      sc[ct] = zz * 0.125f;
    }
#pragma unroll
    for (int ct = 0; ct < 2; ct++)
#pragma unroll
      for (int r = 0; r < 4; r++) {
        float p = __expf(sc[ct][r] - m[r]) * rden[r];
        attn[((size_t)(bh * SEQ + q0 + fg * 4 + r)) * SEQ + kb + ct * 16 + fr] = p;
        P[wave][fg * 4 + r][ct * 16 + fr] = f2bf(p);
      }
    asm volatile("s_waitcnt lgkmcnt(0)" ::: "memory");
    short8 pa = *(const short8*)&P[wave][fr][fg * 8];
#pragma unroll
    for (int dt = 0; dt < 4; dt++) {
      short8 bv = *(const short8*)(Vh + (dt * 16 + fr) * SEQ + kb + fg * 8);
      oacc[dt] = MFMA16(pa, bv, oacc[dt]);
    }
  }

  int b = bh >> 3, h = bh & 7;
#pragma unroll
  for (int dt = 0; dt < 4; dt++)
#pragma unroll
    for (int r = 0; r < 4; r++) {
      int row = q0 + fg * 4 + r;
      ctx[((size_t)(b * SEQ + row)) * DM + h * 64 + dt * 16 + fr] = f2bf(oacc[dt][r]);
    }
}

// ---------------------------------------------------------------------------
// Kernel 3: output projection + bias + residual -> x (f32)
// ---------------------------------------------------------------------------
__global__ __launch_bounds__(256) void oproj_kernel(
    const short* __restrict__ Xbf, const float* __restrict__ W,
    const float* __restrict__ bias, const float* __restrict__ resid,
    float* __restrict__ xout)
{
  __shared__ short As[64][40];
  __shared__ short Bs[64][40];

  int t = threadIdx.x;
  int lane = t & 63, wave = t >> 6;
  int wr = wave >> 1, wc = wave & 1;
  int fr = lane & 15, fg = lane >> 4;
  int m0 = blockIdx.x * 64, n0 = blockIdx.y * 64;
  int lrow = t >> 2, lcol = (t & 3) * 8;

  f32x4 acc[2][2] = {};

  for (int k0 = 0; k0 < DM; k0 += 32) {
    __syncthreads();
    {
      short8 sv = *(const short8*)(Xbf + (size_t)(m0 + lrow) * DM + k0 + lcol);
      *(short8*)&As[lrow][lcol] = sv;
      const float* bp = W + (size_t)(n0 + lrow) * DM + k0 + lcol;
      float4 g0 = *(const float4*)bp;
      float4 g1 = *(const float4*)(bp + 4);
      short8 sb;
      sb[0] = f2bf(g0.x); sb[1] = f2bf(g0.y); sb[2] = f2bf(g0.z); sb[3] = f2bf(g0.w);
      sb[4] = f2bf(g1.x); sb[5] = f2bf(g1.y); sb[6] = f2bf(g1.z); sb[7] = f2bf(g1.w);
      *(short8*)&Bs[lrow][lcol] = sb;
    }
    __syncthreads();
    short8 a0 = *(const short8*)&As[wr * 32 + fr][fg * 8];
    short8 a1 = *(const short8*)&As[wr * 32 + 16 + fr][fg * 8];
    short8 b0 = *(const short8*)&Bs[wc * 32 + fr][fg * 8];
    short8 b1 = *(const short8*)&Bs[wc * 32 + 16 + fr][fg * 8];
    acc[0][0] = MFMA16(a0, b0, acc[0][0]);
    acc[0][1] = MFMA16(a0, b1, acc[0][1]);
    acc[1][0] = MFMA16(a1, b0, acc[1][0]);
    acc[1][1] = MFMA16(a1, b1, acc[1][1]);
  }

#pragma unroll
  for (int mi = 0; mi < 2; mi++)
#pragma unroll
    for (int ni = 0; ni < 2; ni++)
#pragma unroll
      for (int r = 0; r < 4; r++) {
        int row = m0 + wr * 32 + mi * 16 + fg * 4 + r;
        int col = n0 + wc * 32 + ni * 16 + fr;
        float val = acc[mi][ni][r] + bias[col] + resid[(size_t)row * DM + col];
        xout[(size_t)row * DM + col] = val;
      }
}

// ---------------------------------------------------------------------------
// Kernel 4: LayerNorm over last dim (512). One wave per row.
// ---------------------------------------------------------------------------
__global__ __launch_bounds__(256) void ln_kernel(
    const float* __restrict__ x, const float* __restrict__ gamma,
    const float* __restrict__ beta, float* __restrict__ y)
{
  int row = blockIdx.x * 4 + (threadIdx.x >> 6);
  int lane = threadIdx.x & 63;
  const float4* xr = (const float4*)(x + (size_t)row * DM);
  float4 v0 = xr[lane * 2];
  float4 v1 = xr[lane * 2 + 1];
  float s = v0.x + v0.y + v0.z + v0.w + v1.x + v1.y + v1.z + v1.w;
#pragma unroll
  for (int off = 1; off < 64; off <<= 1) s += __shfl_xor(s, off);
  float mean = s * (1.0f / DM);
  float a0 = v0.x - mean, a1 = v0.y - mean, a2 = v0.z - mean, a3 = v0.w - mean;
  float a4 = v1.x - mean, a5 = v1.y - mean, a6 = v1.z - mean, a7 = v1.w - mean;
  float vs = a0 * a0 + a1 * a1 + a2 * a2 + a3 * a3 + a4 * a4 + a5 * a5 + a6 * a6 + a7 * a7;
#pragma unroll
  for (int off = 1; off < 64; off <<= 1) vs += __shfl_xor(vs, off);
  float rstd = rsqrtf(vs * (1.0f / DM) + 1e-5f);
  const float4* gp = (const float4*)gamma;
  const float4* bp = (const float4*)beta;
  float4 g0 = gp[lane * 2], g1 = gp[lane * 2 + 1];
  float4 b0 = bp[lane * 2], b1 = bp[lane * 2 + 1];
  float4 o0, o1;
  o0.x = a0 * rstd * g0.x + b0.x; o0.y = a1 * rstd * g0.y + b0.y;
  o0.z = a2 * rstd * g0.z + b0.z; o0.w = a3 * rstd * g0.w + b0.w;
  o1.x = a4 * rstd * g1.x + b1.x; o1.y = a5 * rstd * g1.y + b1.y;
  o1.z = a6 * rstd * g1.z + b1.z; o1.w = a7 * rstd * g1.w + b1.w;
  float4* yr = (float4*)(y + (size_t)row * DM);
  yr[lane * 2] = o0;
  yr[lane * 2 + 1] = o1;
}

// ---------------------------------------------------------------------------
extern "C" void kernel_launch(void* const* d_in, const int* in_sizes, int n_in,
                              void* d_out, int out_size, void* d_ws, size_t ws_size,
                              hipStream_t stream)
{
  const float* q     = (const float*)d_in[0];
  const float* k     = (const float*)d_in[1];
  const float* v     = (const float*)d_in[2];
  const float* Wq    = (const float*)d_in[3];
  const float* bq    = (const float*)d_in[4];
  const float* Wk    = (const float*)d_in[5];
  const float* bk    = (const float*)d_in[6];
  const float* Wv    = (const float*)d_in[7];
  const float* bv    = (const float*)d_in[8];
  const float* Wo    = (const float*)d_in[9];
  const float* bo    = (const float*)d_in[10];
  const float* gamma = (const float*)d_in[11];
  const float* beta  = (const float*)d_in[12];

  char* w = (char*)d_ws;
  short* Qb   = (short*)(w);                       // 4 MB bf16 [B,H,S,DK]
  short* Kb   = (short*)(w + ((size_t)4 << 20));   // 4 MB
  short* Vtb  = (short*)(w + ((size_t)8 << 20));   // 4 MB [B,H,DK,S]
  short* ctx  = (short*)(w + ((size_t)12 << 20));  // 4 MB bf16 [B,S,DM]
  float* xbuf = (float*)(w + ((size_t)16 << 20));  // 8 MB f32 [NROWS,DM]

  float* y = (float*)d_out;
  float* attnp = y + (size_t)NROWS * DM;  // [B,H,S,S]

  qkv_proj_kernel<<<dim3(64, 8, 3), 256, 0, stream>>>(q, k, v, Wq, Wk, Wv, bq, bk, bv, Qb, Kb, Vtb);
  attn_kernel<<<dim3(32, 16), 256, 0, stream>>>(Qb, Kb, Vtb, attnp, ctx);
  oproj_kernel<<<dim3(64, 8), 256, 0, stream>>>(ctx, Wo, bo, q, xbuf);
  ln_kernel<<<1024, 256, 0, stream>>>(xbuf, gamma, beta, y);
}